// Round 34
// baseline (2491.685 us; speedup 1.0000x reference)
//
#include <hip/hip_runtime.h>

#define DEV __device__ __forceinline__

typedef float f4_t __attribute__((ext_vector_type(4)));

DEV unsigned f2ord(float f){ unsigned u=__float_as_uint(f); return (u&0x80000000u)? ~u : (u|0x80000000u); }
DEV float ord2f(unsigned o){ unsigned u=(o&0x80000000u)? (o&0x7FFFFFFFu) : ~o; return __uint_as_float(u); }
DEV float wsum(float v){ for(int o=32;o;o>>=1) v+=__shfl_down(v,o,64); return v; }
DEV float wminr(float v){ for(int o=32;o;o>>=1) v=fminf(v,__shfl_down(v,o,64)); return v; }
DEV float wmaxr(float v){ for(int o=32;o;o>>=1) v=fmaxf(v,__shfl_down(v,o,64)); return v; }

// ---------------- init ----------------
__global__ void k_init(float* counts, unsigned* mnmx){
  int i = threadIdx.x;
  if (i < 512) counts[i] = 0.f;
  if (i < 48) mnmx[i] = 0xFFFFFFFFu;
  if (i >= 64 && i < 112) mnmx[i-64+48] = 0u;
}
__global__ void k_initvq(unsigned long long* keys){
  int i = blockIdx.x*256 + threadIdx.x;
  keys[i] = ~0ull;
}

// ---------------- front ----------------
__global__ __launch_bounds__(256) void k_taylor(const float* __restrict__ x, const float* __restrict__ tc,
                                                float* __restrict__ t, float* __restrict__ gpart){
  int blk = blockIdx.x;
  int bc = blk >> 6, chunk = blk & 63;
  float k0=tc[0], k1=tc[1], k2=tc[2]*0.5f, k3=tc[3]*(1.f/6.f), k4=tc[4]*(1.f/24.f);
  size_t base = (size_t)bc*65536 + (size_t)chunk*1024;
  float s = 0.f;
  #pragma unroll
  for (int j=0;j<4;j++){
    size_t i = base + threadIdx.x + j*256;
    float xv = x[i];
    float tv = k0 + xv*(k1 + xv*(k2 + xv*(k3 + xv*k4)));
    t[i] = tv; s += tv;
  }
  s = wsum(s);
  __shared__ float ws4[4];
  int lane = threadIdx.x & 63, wv = threadIdx.x >> 6;
  if (lane==0) ws4[wv]=s;
  __syncthreads();
  if (threadIdx.x==0) gpart[blk] = ws4[0]+ws4[1]+ws4[2]+ws4[3];
}

__global__ void k_chw(const float* __restrict__ gpart, const float* __restrict__ w1, const float* __restrict__ b1,
                      const float* __restrict__ w2, const float* __restrict__ b2,
                      const float* __restrict__ bng, const float* __restrict__ bnb,
                      const float* __restrict__ bnm, const float* __restrict__ bnv,
                      float* __restrict__ chw, float* __restrict__ bnsb){
  __shared__ float g[80];
  int tid = threadIdx.x; // 128
  if (tid < 80){
    float s = 0.f;
    for (int j=0;j<64;j++) s += gpart[tid*64+j];
    g[tid] = s * (1.f/65536.f);
  }
  __syncthreads();
  if (tid < 16){
    int b = tid;
    float h[4];
    for (int j=0;j<4;j++){
      float a = b1[j];
      for (int c=0;c<5;c++) a += g[b*5+c]*w1[j*5+c];
      h[j] = fmaxf(a, 0.f);
    }
    for (int c=0;c<5;c++){
      float a = b2[c];
      for (int j=0;j<4;j++) a += h[j]*w2[c*4+j];
      chw[b*5+c] = 1.f/(1.f+expf(-a));
    }
  } else if (tid >= 32 && tid < 35){
    int c = tid-32;
    float sc = bng[c] / sqrtf(bnv[c] + 1e-5f);
    bnsb[c] = sc;
    bnsb[4+c] = bnb[c] - bnm[c]*sc;
  }
}

__global__ __launch_bounds__(256) void k_spin(float* __restrict__ t, const float* __restrict__ chw,
                                              float* __restrict__ spm, float* __restrict__ spx){
  int b = blockIdx.y;
  int p = blockIdx.x*256 + threadIdx.x;
  size_t base = ((size_t)b*5)*65536 + p;
  float vs=0.f, vmax=-3.0e38f;
  #pragma unroll
  for (int c=0;c<5;c++){
    float v = t[base + (size_t)c*65536] * chw[b*5+c];
    t[base + (size_t)c*65536] = v;
    vs += v; vmax = fmaxf(vmax, v);
  }
  spm[(size_t)b*65536+p] = vs*0.2f;
  spx[(size_t)b*65536+p] = vmax;
}

__global__ __launch_bounds__(256) void k_sa(const float* __restrict__ spm, const float* __restrict__ spx,
                                            const float* __restrict__ w, const float* __restrict__ bias,
                                            float* __restrict__ samap){
  int b = blockIdx.y;
  int p = blockIdx.x*256 + threadIdx.x;
  int y0 = p >> 8, x0 = p & 255;
  float acc = bias[0];
  const float* sp0 = spm + (size_t)b*65536;
  const float* sp1 = spx + (size_t)b*65536;
  #pragma unroll
  for (int ky=0;ky<7;ky++){
    int iy = y0 - 3 + ky;
    if ((unsigned)iy >= 256u) continue;
    #pragma unroll
    for (int kx=0;kx<7;kx++){
      int ix = x0 - 3 + kx;
      if ((unsigned)ix >= 256u) continue;
      acc += sp0[iy*256+ix] * w[ky*7+kx] + sp1[iy*256+ix] * w[49+ky*7+kx];
    }
  }
  samap[(size_t)b*65536+p] = 1.f/(1.f+expf(-acc));
}

__global__ __launch_bounds__(256) void k_mix(const float* __restrict__ t, const float* __restrict__ samap,
                                             const float* __restrict__ mw, const float* __restrict__ mb,
                                             const float* __restrict__ bnsb, float* __restrict__ t3,
                                             unsigned* __restrict__ mnmx){
  int b = blockIdx.y;
  int p = blockIdx.x*256 + threadIdx.x;
  float s = samap[(size_t)b*65536+p];
  float v[5];
  #pragma unroll
  for (int c=0;c<5;c++) v[c] = t[((size_t)b*5+c)*65536+p] * s;
  float mn[3], mx[3];
  #pragma unroll
  for (int co=0;co<3;co++){
    float a = mb[co];
    #pragma unroll
    for (int ci=0;ci<5;ci++) a += v[ci]*mw[co*5+ci];
    a = a*bnsb[co] + bnsb[4+co];
    a = (a >= 0.f) ? a : 0.1f*a;
    t3[((size_t)b*3+co)*65536+p] = a;
    mn[co]=a; mx[co]=a;
  }
  __shared__ float smn[3][4], smx[3][4];
  int lane = threadIdx.x & 63, wv = threadIdx.x >> 6;
  #pragma unroll
  for (int co=0;co<3;co++){
    float lmn = wminr(mn[co]);
    float lmx = wmaxr(mx[co]);
    if (lane==0){ smn[co][wv]=lmn; smx[co][wv]=lmx; }
  }
  __syncthreads();
  if (threadIdx.x==0){
    #pragma unroll
    for (int co=0;co<3;co++){
      float m0 = fminf(fminf(smn[co][0],smn[co][1]),fminf(smn[co][2],smn[co][3]));
      float m1 = fmaxf(fmaxf(smx[co][0],smx[co][1]),fmaxf(smx[co][2],smx[co][3]));
      atomicMin(&mnmx[b*3+co], f2ord(m0));
      atomicMax(&mnmx[48+b*3+co], f2ord(m1));
    }
  }
}

__global__ __launch_bounds__(256) void k_norm(float* __restrict__ t3, const unsigned* __restrict__ mnmx){
  int i = blockIdx.x*256 + threadIdx.x;
  int bc = i >> 16;
  float mn = ord2f(mnmx[bc]);
  float mx = ord2f(mnmx[48+bc]);
  t3[i] = (t3[i] - mn) / (mx - mn + 1e-4f);
}

// ---------------- weight packing ----------------
__global__ void k_pack(const float* __restrict__ w, float* __restrict__ wt, int CIN, int COUT, int KHW){
  int i = blockIdx.x*256 + threadIdx.x;
  int total = CIN*COUT*KHW;
  if (i >= total) return;
  int co = i % COUT; int tt = i / COUT;
  int ci = tt / KHW, k = tt % KHW;
  wt[i] = w[(co*CIN + ci)*KHW + k];
}
__global__ void k_pack_d1(const float* __restrict__ w, float* __restrict__ wt){
  int i = blockIdx.x*256 + threadIdx.x; // 64*9*128
  if (i >= 64*9*128) return;
  int co = i & 127; int tt = i >> 7;
  int ci = tt / 9, k = tt % 9;
  int ky = k/3, kx = k%3;
  wt[i] = w[(ci*128 + co)*9 + (2-ky)*3 + (2-kx)];
}
// d2 per-parity pack: out[par][(ci*4 + kyp*2+kxp)*64 + co], ky = 3-py-2*kyp, kx = 3-px-2*kxp
__global__ void k_pack_d2p(const float* __restrict__ w, float* __restrict__ wt){
  int i = blockIdx.x*256 + threadIdx.x; // 4*128*4*64 = 131072
  if (i >= 131072) return;
  int co = i & 63; int t = i >> 6;
  int kk = t & 3; int t2 = t >> 2;
  int ci = t2 & 127; int par = t2 >> 7;
  int py = par >> 1, px = par & 1;
  int kyp = kk >> 1, kxp = kk & 1;
  int ky = 3 - py - 2*kyp;
  int kx = 3 - px - 2*kxp;
  wt[i] = w[((size_t)ci*64 + co)*16 + ky*4 + kx];
}
// d3 per-parity pack: out[par][(ci*4 + kyp*2+kxp)*5 + co], same tap algebra as d2p; COUT=5
__global__ void k_pack_d3p(const float* __restrict__ w, float* __restrict__ wt){
  int i = blockIdx.x*256 + threadIdx.x; // 4*64*4*5 = 5120
  if (i >= 5120) return;
  int co = i % 5; int t = i / 5;
  int kk = t & 3; int t2 = t >> 2;
  int ci = t2 & 63; int par = t2 >> 6;
  int py = par >> 1, px = par & 1;
  int kyp = kk >> 1, kxp = kk & 1;
  int ky = 3 - py - 2*kyp;
  int kx = 3 - px - 2*kxp;
  wt[i] = w[((size_t)ci*5 + co)*16 + ky*4 + kx];
}
__global__ void k_cb2(const float* __restrict__ cb, float* __restrict__ cb2){
  int c = blockIdx.x*64 + threadIdx.x;
  if (c >= 512) return;
  float s=0.f;
  for (int d=0; d<64; d++){ float v = cb[c*64+d]; s += v*v; }
  cb2[c] = s;
}

// ---------------- e1 direct conv, 16 co per thread ----------------
__global__ __launch_bounds__(256) void convk16(const float* __restrict__ x, const float* __restrict__ wt,
                                               const float* __restrict__ bias, float* __restrict__ y){
  int p = blockIdx.x*256 + threadIdx.x;   // 16384 output pixels (128x128)
  int oy = p >> 7, ox = p & 127;
  int co = blockIdx.y*16;
  int n  = blockIdx.z;
  const float* xn = x + (size_t)n*3*65536;
  f4_t a0 = *(const f4_t*)&bias[co];
  f4_t a1 = *(const f4_t*)&bias[co+4];
  f4_t a2 = *(const f4_t*)&bias[co+8];
  f4_t a3 = *(const f4_t*)&bias[co+12];
  #pragma unroll
  for (int ky=0; ky<4; ky++){
    int iy = oy*2 - 1 + ky;
    bool rok = (unsigned)iy < 256u;
    #pragma unroll
    for (int kx=0; kx<4; kx++){
      int ix = ox*2 - 1 + kx;
      bool ok = rok && ((unsigned)ix < 256u);
      const float* xp = xn + (size_t)iy*256 + ix;
      const float* wp = wt + (ky*4 + kx)*64 + co;
      #pragma unroll
      for (int ci=0; ci<3; ci++){
        float v = ok ? xp[ci*65536] : 0.f;
        const f4_t w0 = *(const f4_t*)(wp + ci*1024);
        const f4_t w1 = *(const f4_t*)(wp + ci*1024 + 4);
        const f4_t w2 = *(const f4_t*)(wp + ci*1024 + 8);
        const f4_t w3 = *(const f4_t*)(wp + ci*1024 + 12);
        a0 += v*w0; a1 += v*w1; a2 += v*w2; a3 += v*w3;
      }
    }
  }
  size_t yb = ((size_t)n*64 + co)*16384 + p;
  #pragma unroll
  for (int j=0;j<16;j++){
    float av = (j<4) ? ((const float*)&a0)[j]
             : (j<8) ? ((const float*)&a1)[j-4]
             : (j<12)? ((const float*)&a2)[j-8]
             :         ((const float*)&a3)[j-12];
    y[yb + (size_t)j*16384] = fmaxf(av, 0.f);
  }
}

// ---------------- tiled conv v2: thread = ROWS rows x 8 co, per-instantiation unroll U ------
template<int CIN,int COUT,int KH,int KW,int PY,int PX,int ROWS,int U,bool RIN,bool ROUT,bool ADD>
__global__ __launch_bounds__(256) void conv8(const float* __restrict__ x, const float* __restrict__ wt,
                                             const float* __restrict__ bias, const float* __restrict__ res,
                                             float* __restrict__ y,
                                             int plane, int rstr, int cstr, int obase){
  constexpr int KHW = KH*KW;
  constexpr int NR  = KH + ROWS - 1;
  int tid = threadIdx.x;
  int cob = blockIdx.y*8;
  int ox  = tid & 63;
  int oy0 = blockIdx.x*(4*ROWS) + (tid>>6)*ROWS;
  int n   = blockIdx.z;
  const float* xn = x + (size_t)n*CIN*4096;
  f4_t b0 = *(const f4_t*)&bias[cob];
  f4_t b1 = *(const f4_t*)&bias[cob+4];
  f4_t acc0[ROWS], acc1[ROWS];
  #pragma unroll
  for (int r=0;r<ROWS;r++){ acc0[r] = b0; acc1[r] = b1; }

  for (int cb0=0; cb0<CIN; cb0+=U){
    #pragma unroll
    for (int u=0; u<U; u++){
      int ci = cb0 + u;
      const float* xc = xn + (size_t)ci*4096;
      float c0[NR], cl[NR], cr[NR];
      #pragma unroll
      for (int rr=0; rr<NR; rr++){
        int iy = oy0 - PY + rr;
        bool vr = (unsigned)iy < 64u;
        float v = vr ? xc[iy*64 + ox] : 0.f;
        if (RIN) v = fmaxf(v, 0.f);
        c0[rr] = v;
      }
      #pragma unroll
      for (int rr=0; rr<NR; rr++){
        if (KW == 3){
          float l = __shfl_up(c0[rr], 1, 64);   if (ox==0)  l = 0.f;
          float g = __shfl_down(c0[rr], 1, 64); if (ox==63) g = 0.f;
          cl[rr] = l; cr[rr] = g;
        } else if (KW == 2){
          float s;
          if (PX == 1){ s = __shfl_up(c0[rr], 1, 64);   if (ox==0)  s = 0.f; }
          else        { s = __shfl_down(c0[rr], 1, 64); if (ox==63) s = 0.f; }
          cl[rr] = s;
        }
      }
      const float* wci = wt + (size_t)ci*KHW*COUT + cob;
      #pragma unroll
      for (int ky=0; ky<KH; ky++){
        #pragma unroll
        for (int kx=0; kx<KW; kx++){
          f4_t w0 = *(const f4_t*)(wci + (ky*KW + kx)*COUT);
          f4_t w1 = *(const f4_t*)(wci + (ky*KW + kx)*COUT + 4);
          #pragma unroll
          for (int r=0; r<ROWS; r++){
            int rr = r + ky;
            float v;
            if (KW == 1)      v = c0[rr];
            else if (KW == 3) v = (kx==0) ? cl[rr] : ((kx==1) ? c0[rr] : cr[rr]);
            else              v = (kx==PX) ? c0[rr] : cl[rr];
            acc0[r] += v * w0;
            acc1[r] += v * w1;
          }
        }
      }
    }
  }

  #pragma unroll
  for (int r=0;r<ROWS;r++){
    size_t base = ((size_t)n*COUT + cob)*plane + (size_t)(oy0+r)*rstr + obase + ox*cstr;
    #pragma unroll
    for (int j=0;j<8;j++){
      float a = (j<4) ? ((const float*)&acc0[r])[j] : ((const float*)&acc1[r])[j-4];
      if (ROUT) a = fmaxf(a, 0.f);
      if (ADD)  a += res[base + (size_t)j*plane];
      y[base + (size_t)j*plane] = a;
    }
  }
}

// ---------------- tiled conv v2: e2 (128x128 -> 64x64, k=4 s=2 p=1), ROWS rows x 8 co ----------
// Round-34: ci unroll 2->4 (grid-limited at 4 waves/SIMD -> VGPR free to 128; doubles
// in-flight load batch against the ~55% latency-stall fraction).
template<int CIN,int COUT,int ROWS,bool RIN,bool ROUT>
__global__ __launch_bounds__(256) void conv8s2(const float* __restrict__ x, const float* __restrict__ wt,
                                               const float* __restrict__ bias, float* __restrict__ y){
  constexpr int NRI = 2*ROWS + 2;
  int tid = threadIdx.x;
  int cob = blockIdx.y*8;
  int ox  = tid & 63;
  int oy0 = blockIdx.x*(4*ROWS) + (tid>>6)*ROWS;
  int n   = blockIdx.z;
  const float* xn = x + (size_t)n*CIN*16384;
  f4_t b0 = *(const f4_t*)&bias[cob];
  f4_t b1 = *(const f4_t*)&bias[cob+4];
  f4_t acc0[ROWS], acc1[ROWS];
  #pragma unroll
  for (int r=0;r<ROWS;r++){ acc0[r] = b0; acc1[r] = b1; }

  #pragma unroll 4
  for (int ci=0; ci<CIN; ci++){
    const float* xc = xn + (size_t)ci*16384;
    float A[NRI], Bb[NRI], L[NRI], R[NRI];
    #pragma unroll
    for (int rr=0; rr<NRI; rr++){
      int iy = 2*oy0 - 1 + rr;
      bool vr = (unsigned)iy < 128u;
      float a = 0.f, b = 0.f;
      if (vr){
        float2 ab = *(const float2*)(xc + iy*128 + 2*ox);
        a = ab.x; b = ab.y;
      }
      if (RIN){ a = fmaxf(a,0.f); b = fmaxf(b,0.f); }
      A[rr] = a; Bb[rr] = b;
    }
    #pragma unroll
    for (int rr=0; rr<NRI; rr++){
      float l = __shfl_up(Bb[rr], 1, 64);  if (ox==0)  l = 0.f;   // ix = 2ox-1
      float g = __shfl_down(A[rr], 1, 64); if (ox==63) g = 0.f;   // ix = 2ox+2
      L[rr] = l; R[rr] = g;
    }
    const float* wci = wt + (size_t)ci*16*COUT + cob;
    #pragma unroll
    for (int ky=0; ky<4; ky++){
      #pragma unroll
      for (int kx=0; kx<4; kx++){
        f4_t w0 = *(const f4_t*)(wci + (ky*4 + kx)*COUT);
        f4_t w1 = *(const f4_t*)(wci + (ky*4 + kx)*COUT + 4);
        #pragma unroll
        for (int r=0; r<ROWS; r++){
          int rr = 2*r + ky;
          float v = (kx==0) ? L[rr] : ((kx==1) ? A[rr] : ((kx==2) ? Bb[rr] : R[rr]));
          acc0[r] += v * w0;
          acc1[r] += v * w1;
        }
      }
    }
  }

  #pragma unroll
  for (int r=0;r<ROWS;r++){
    size_t base = ((size_t)n*COUT + cob)*4096 + (size_t)(oy0+r)*64 + ox;
    #pragma unroll
    for (int j=0;j<8;j++){
      float a = (j<4) ? ((const float*)&acc0[r])[j] : ((const float*)&acc1[r])[j-4];
      if (ROUT) a = fmaxf(a, 0.f);
      y[base + (size_t)j*4096] = a;
    }
  }
}

// ---------------- d2 ConvTranspose: BOTH px parities per block, ROWS=4 ----------
__global__ __launch_bounds__(256) void convd2p(const float* __restrict__ x, const float* __restrict__ wt,
                                               const float* __restrict__ bias, float* __restrict__ y){
  constexpr int ROWS = 4;
  constexpr int NR   = ROWS + 1;   // KH=2
  int py   = blockIdx.y >> 3;
  int cob  = (blockIdx.y & 7)*8;
  int PY   = 1 - py;
  const float* wpA = wt + (size_t)(py*2    )*32768;   // px=0 parity
  const float* wpB = wt + (size_t)(py*2 + 1)*32768;   // px=1 parity
  int tid = threadIdx.x;
  int ox  = tid & 63;
  int oy0 = blockIdx.x*(4*ROWS) + (tid>>6)*ROWS;
  int n   = blockIdx.z;
  const float* xn = x + (size_t)n*128*4096;
  f4_t b0 = *(const f4_t*)&bias[cob];
  f4_t b1 = *(const f4_t*)&bias[cob+4];
  f4_t aA0[ROWS], aA1[ROWS], aB0[ROWS], aB1[ROWS];
  #pragma unroll
  for (int r=0;r<ROWS;r++){ aA0[r]=b0; aA1[r]=b1; aB0[r]=b0; aB1[r]=b1; }

  #pragma unroll 2
  for (int ci=0; ci<128; ci++){
    const float* xc = xn + (size_t)ci*4096;
    float c0[NR], cl[NR], cr[NR];
    #pragma unroll
    for (int rr=0; rr<NR; rr++){
      int iy = oy0 - PY + rr;
      bool vr = (unsigned)iy < 64u;
      float v = vr ? xc[iy*64 + ox] : 0.f;
      c0[rr] = fmaxf(v, 0.f);                 // RIN (input is pre-ReLU dh1)
    }
    #pragma unroll
    for (int rr=0; rr<NR; rr++){
      float su = __shfl_up(c0[rr], 1, 64);   if (ox==0)  su = 0.f;
      float sd = __shfl_down(c0[rr], 1, 64); if (ox==63) sd = 0.f;
      cl[rr] = su; cr[rr] = sd;
    }
    const float* wciA = wpA + (size_t)ci*256 + cob;
    const float* wciB = wpB + (size_t)ci*256 + cob;
    #pragma unroll
    for (int ky=0; ky<2; ky++){
      #pragma unroll
      for (int kx=0; kx<2; kx++){
        f4_t w0 = *(const f4_t*)(wciA + (ky*2 + kx)*64);
        f4_t w1 = *(const f4_t*)(wciA + (ky*2 + kx)*64 + 4);
        #pragma unroll
        for (int r=0; r<ROWS; r++){
          int rr = r + ky;
          float v = (kx == 1) ? c0[rr] : cl[rr];
          aA0[r] += v * w0;
          aA1[r] += v * w1;
        }
      }
    }
    #pragma unroll
    for (int ky=0; ky<2; ky++){
      #pragma unroll
      for (int kx=0; kx<2; kx++){
        f4_t w0 = *(const f4_t*)(wciB + (ky*2 + kx)*64);
        f4_t w1 = *(const f4_t*)(wciB + (ky*2 + kx)*64 + 4);
        #pragma unroll
        for (int r=0; r<ROWS; r++){
          int rr = r + ky;
          float v = (kx == 0) ? c0[rr] : cr[rr];
          aB0[r] += v * w0;
          aB1[r] += v * w1;
        }
      }
    }
  }

  #pragma unroll
  for (int r=0;r<ROWS;r++){
    size_t rowb = ((size_t)n*64 + cob)*16384 + (size_t)(oy0+r)*256 + py*128 + ox*2;
    #pragma unroll
    for (int j=0;j<8;j++){
      float a = (j<4) ? ((const float*)&aA0[r])[j] : ((const float*)&aA1[r])[j-4];
      float b = (j<4) ? ((const float*)&aB0[r])[j] : ((const float*)&aB1[r])[j-4];
      float2 v2; v2.x = fmaxf(a, 0.f); v2.y = fmaxf(b, 0.f);   // ROUT
      *(float2*)&y[rowb + (size_t)j*16384] = v2;
    }
  }
}

// ---------------- d3 ConvTranspose k=4 s=2 p=1, ALL 4 parities in one launch ----------------
__global__ __launch_bounds__(256) void convd3(const float* __restrict__ x, const float* __restrict__ wt,
                                              const float* __restrict__ bias, float* __restrict__ y){
  constexpr int ROWS = 2;
  constexpr int NRI  = ROWS + 1;
  int par  = blockIdx.y;
  int py   = par >> 1, px = par & 1;
  int PY   = 1 - py,  PX = 1 - px;
  const float* wpar = wt + par*1280;
  int tid  = threadIdx.x;
  int lane = tid & 63, wv = tid >> 6;
  int oy0  = blockIdx.x*(4*ROWS) + wv*ROWS;
  int n    = blockIdx.z;
  const float* xn = x + (size_t)n*64*16384;
  float b[5];
  #pragma unroll
  for (int j=0;j<5;j++) b[j] = bias[j];
  float acc[ROWS][2][5];
  #pragma unroll
  for (int r=0;r<ROWS;r++)
    #pragma unroll
    for (int c=0;c<2;c++)
      #pragma unroll
      for (int j=0;j<5;j++) acc[r][c][j] = b[j];

  #pragma unroll 2
  for (int ci=0; ci<64; ci++){
    const float* xc = xn + (size_t)ci*16384;
    float A[NRI], Bv[NRI], S[NRI];
    #pragma unroll
    for (int rr=0; rr<NRI; rr++){
      int iy = oy0 - PY + rr;
      float a = 0.f, bb = 0.f;
      if ((unsigned)iy < 128u){
        float2 ab = *(const float2*)(xc + iy*128 + 2*lane);
        a = ab.x; bb = ab.y;
      }
      A[rr] = a; Bv[rr] = bb;
    }
    if (PX == 1){
      #pragma unroll
      for (int rr=0; rr<NRI; rr++){
        float l = __shfl_up(Bv[rr], 1, 64); if (lane==0) l = 0.f;
        S[rr] = l;                       // L: ix = 2*lane-1
      }
    } else {
      #pragma unroll
      for (int rr=0; rr<NRI; rr++){
        float g = __shfl_down(A[rr], 1, 64); if (lane==63) g = 0.f;
        S[rr] = g;                       // R: ix = 2*lane+2
      }
    }
    const float* wci = wpar + ci*20;
    #pragma unroll
    for (int kyp=0; kyp<2; kyp++){
      #pragma unroll
      for (int kxp=0; kxp<2; kxp++){
        const float* wp = wci + (kyp*2 + kxp)*5;
        #pragma unroll
        for (int r=0; r<ROWS; r++){
          int rr = r + kyp;
          float v0, v1;
          if (PX == 1){ v0 = (kxp==0) ? S[rr]  : A[rr];  v1 = (kxp==0) ? A[rr]  : Bv[rr]; }
          else        { v0 = (kxp==0) ? A[rr]  : Bv[rr]; v1 = (kxp==0) ? Bv[rr] : S[rr];  }
          #pragma unroll
          for (int j=0;j<5;j++){
            acc[r][0][j] = fmaf(v0, wp[j], acc[r][0][j]);
            acc[r][1][j] = fmaf(v1, wp[j], acc[r][1][j]);
          }
        }
      }
    }
  }

  #pragma unroll
  for (int r=0;r<ROWS;r++){
    size_t rowb = (size_t)n*5*65536 + (size_t)(2*(oy0+r)+py)*256;
    #pragma unroll
    for (int j=0;j<5;j++){
      y[rowb + (size_t)j*65536 + 4*lane + px]     = acc[r][0][j];
      y[rowb + (size_t)j*65536 + 4*lane + 2 + px] = acc[r][1][j];
    }
  }
}

// ---------------- VQ: codebook split across BLOCKS, rows stay 1/thread (round-26) ----------
__global__ __launch_bounds__(256) void k_vqscan(const float* __restrict__ zenc, const float* __restrict__ cb,
                                                const float* __restrict__ cb2,
                                                unsigned long long* __restrict__ keys){
  int r = blockIdx.x*256 + threadIdx.x;
  int q = blockIdx.y;
  int b = r >> 12, p = r & 4095;
  const float* zp = zenc + ((size_t)b*64)*4096 + p;
  float z[64];
  float z2 = 0.f;
  #pragma unroll
  for (int d=0; d<64; d++){ z[d] = zp[(size_t)d*4096]; z2 += z[d]*z[d]; }
  float best = 3.4e38f; int bi = 0;
  int cbeg = q*128;
  for (int c=cbeg; c<cbeg+128; c+=4){
    float dot0=0.f, dot1=0.f, dot2=0.f, dot3=0.f;
    const float* c0 = cb + c*64;
    #pragma unroll
    for (int d=0; d<64; d++){
      float zd = z[d];
      dot0 = fmaf(zd, c0[d],     dot0);
      dot1 = fmaf(zd, c0[64+d],  dot1);
      dot2 = fmaf(zd, c0[128+d], dot2);
      dot3 = fmaf(zd, c0[192+d], dot3);
    }
    float d0 = (z2 + cb2[c])   - 2.f*dot0;
    float d1 = (z2 + cb2[c+1]) - 2.f*dot1;
    float d2 = (z2 + cb2[c+2]) - 2.f*dot2;
    float d3 = (z2 + cb2[c+3]) - 2.f*dot3;
    if (d0 < best){ best = d0; bi = c; }
    if (d1 < best){ best = d1; bi = c+1; }
    if (d2 < best){ best = d2; bi = c+2; }
    if (d3 < best){ best = d3; bi = c+3; }
  }
  unsigned long long key = ((unsigned long long)f2ord(best) << 32) | (unsigned long long)(unsigned)bi;
  atomicMin(&keys[r], key);
}

__global__ __launch_bounds__(256) void k_vqfin(const float* __restrict__ zenc, const float* __restrict__ cb,
                                               const unsigned long long* __restrict__ keys,
                                               int* __restrict__ idx, float* __restrict__ lossp,
                                               float* __restrict__ counts){
  int r = blockIdx.x*256 + threadIdx.x;
  int b = r >> 12, p = r & 4095;
  int bi = (int)(keys[r] & 0xFFFFFFFFull);
  idx[r] = bi;
  const float* zp = zenc + ((size_t)b*64)*4096 + p;
  const float* cbest = cb + bi*64;
  float l = 0.f;
  #pragma unroll
  for (int d=0; d<64; d++){ float df = zp[(size_t)d*4096] - cbest[d]; l = fmaf(df,df,l); }
  l = wsum(l);
  __shared__ float ls[4];
  __shared__ int hist[512];
  int lane = threadIdx.x & 63, wv = threadIdx.x >> 6;
  if (lane==0) ls[wv] = l;
  for (int i=threadIdx.x; i<512; i+=256) hist[i]=0;
  __syncthreads();
  atomicAdd(&hist[bi], 1);
  if (threadIdx.x==0) lossp[blockIdx.x] = ls[0]+ls[1]+ls[2]+ls[3];
  __syncthreads();
  for (int i=threadIdx.x; i<512; i+=256){
    int h = hist[i];
    if (h) atomicAdd(&counts[i], (float)h);
  }
}

__global__ void k_finalize(const float* __restrict__ counts, const float* __restrict__ lossp,
                           float* __restrict__ out){
  __shared__ float sl[8], st[8];
  int tid = threadIdx.x; // 512
  int lane = tid & 63, wv = tid >> 6;
  float lp = (tid < 256) ? lossp[tid] : 0.f;
  lp = wsum(lp);
  if (lane==0) sl[wv] = lp;
  float pr = counts[tid] * (1.f/65536.f);
  float term = pr * logf(pr + 1e-10f);
  term = wsum(term);
  if (lane==0) st[wv] = term;
  __syncthreads();
  if (tid==0){
    float L=0.f, S=0.f;
    for (int i=0;i<8;i++){ L += sl[i]; S += st[i]; }
    out[5242880] = L * 0.25f / (65536.f*64.f);
    out[5242881] = expf(-S);
  }
}

__global__ __launch_bounds__(256) void k_gather(const float* __restrict__ cb, const int* __restrict__ idx,
                                                float* __restrict__ zq){
  int i = blockIdx.x*256 + threadIdx.x;
  int p = i & 4095;
  int d = (i >> 12) & 63;
  int b = i >> 18;
  zq[i] = cb[idx[(b<<12) + p]*64 + d];
}

// ---------------- launch ----------------
extern "C" void kernel_launch(void* const* d_in, const int* in_sizes, int n_in,
                              void* d_out, int out_size, void* d_ws, size_t ws_size,
                              hipStream_t stream){
  (void)in_sizes; (void)n_in; (void)out_size;
  const float* x     = (const float*)d_in[0];
  const float* tc    = (const float*)d_in[1];
  const float* ca_w1 = (const float*)d_in[2];
  const float* ca_b1 = (const float*)d_in[3];
  const float* ca_w2 = (const float*)d_in[4];
  const float* ca_b2 = (const float*)d_in[5];
  const float* sa_w  = (const float*)d_in[6];
  const float* sa_b  = (const float*)d_in[7];
  const float* mix_w = (const float*)d_in[8];
  const float* mix_b = (const float*)d_in[9];
  const float* bn_g  = (const float*)d_in[10];
  const float* bn_b  = (const float*)d_in[11];
  const float* bn_m  = (const float*)d_in[12];
  const float* bn_v  = (const float*)d_in[13];
  const float* e1_w  = (const float*)d_in[14];
  const float* e1_b  = (const float*)d_in[15];
  const float* e2_w  = (const float*)d_in[16];
  const float* e2_b  = (const float*)d_in[17];
  const float* e3_w  = (const float*)d_in[18];
  const float* e3_b  = (const float*)d_in[19];
  const float* er1a_w= (const float*)d_in[20];
  const float* er1a_b= (const float*)d_in[21];
  const float* er1b_w= (const float*)d_in[22];
  const float* er1b_b= (const float*)d_in[23];
  const float* er2a_w= (const float*)d_in[24];
  const float* er2a_b= (const float*)d_in[25];
  const float* er2b_w= (const float*)d_in[26];
  const float* er2b_b= (const float*)d_in[27];
  const float* ep_w  = (const float*)d_in[28];
  const float* ep_b  = (const float*)d_in[29];
  const float* cb    = (const float*)d_in[30];
  const float* d1_w  = (const float*)d_in[31];
  const float* d1_b  = (const float*)d_in[32];
  const float* dr1a_w= (const float*)d_in[33];
  const float* dr1a_b= (const float*)d_in[34];
  const float* dr1b_w= (const float*)d_in[35];
  const float* dr1b_b= (const float*)d_in[36];
  const float* dr2a_w= (const float*)d_in[37];
  const float* dr2a_b= (const float*)d_in[38];
  const float* dr2b_w= (const float*)d_in[39];
  const float* dr2b_b= (const float*)d_in[40];
  const float* d2_w  = (const float*)d_in[41];
  const float* d2_b  = (const float*)d_in[42];
  const float* d3_w  = (const float*)d_in[43];
  const float* d3_b  = (const float*)d_in[44];
  float* out = (float*)d_out;
  float* ws = (float*)d_ws;

  size_t o = 0;
  auto alloc = [&](size_t n){ size_t r = o; o += (n + 63) & ~63ull; return r; };
  size_t f_buf0 = alloc(16777216);  // h1 (16,64,128,128); later zq head, then d2 out
  size_t f_buf1 = alloc(8388608);   // h2 (16,128,64,64); later dh1
  size_t f_buf2 = alloc(8388608);   // h3
  size_t f_buf3 = alloc(5242880);   // t (16,5,256,256); later zenc (16,64,64,64)
  size_t f_buf4 = alloc(3145728);   // t3 (16,3,256,256)
  size_t f_spm  = alloc(1048576);
  size_t f_spx  = alloc(1048576);
  size_t f_sam  = alloc(1048576);
  size_t f_gpart= alloc(5120);
  size_t f_chw  = alloc(80);
  size_t f_bnsb = alloc(8);
  size_t f_mnmx = alloc(96);
  size_t f_counts=alloc(512);
  size_t f_lossp= alloc(256);
  size_t f_cb2  = alloc(512);
  size_t f_idx  = alloc(65536);
  size_t f_vqkey= alloc(131072);    // 65536 x u64 keys
  size_t f_wt_e1= alloc(3072);
  size_t f_wt_e2= alloc(131072);
  size_t f_wt_e3= alloc(147456);
  size_t f_wt_ra1=alloc(36864);
  size_t f_wt_rb1=alloc(4096);
  size_t f_wt_ra2=alloc(36864);
  size_t f_wt_rb2=alloc(4096);
  size_t f_wt_ep= alloc(8192);
  size_t f_wt_d1= alloc(73728);
  size_t f_wt_da1=alloc(36864);
  size_t f_wt_db1=alloc(4096);
  size_t f_wt_da2=alloc(36864);
  size_t f_wt_db2=alloc(4096);
  size_t f_wt_d2= alloc(131072);
  size_t f_wt_d3= alloc(5120);
  if (ws_size < o*sizeof(float)) return;

  float* t    = ws + f_buf3;
  float* zenc = ws + f_buf3;
  float* h1   = ws + f_buf0;
  float* zq   = ws + f_buf0;
  float* dh2  = ws + f_buf0;
  float* h2   = ws + f_buf1;
  float* dh1  = ws + f_buf1;
  float* h3   = ws + f_buf2;
  float* t3   = ws + f_buf4;
  float* spm  = ws + f_spm;
  float* spx  = ws + f_spx;
  float* rtmp = ws + f_spm;
  float* samap= ws + f_sam;
  unsigned* mnmx = (unsigned*)(ws + f_mnmx);
  int* idx = (int*)(ws + f_idx);
  unsigned long long* vqkeys = (unsigned long long*)(ws + f_vqkey);

  dim3 T(256);

  k_init<<<1, 512, 0, stream>>>(ws + f_counts, mnmx);
  k_initvq<<<256, T, 0, stream>>>(vqkeys);

  // weight packs
  k_pack<<<(3072+255)/256, T, 0, stream>>>(e1_w, ws+f_wt_e1, 3, 64, 16);
  k_pack<<<(131072+255)/256, T, 0, stream>>>(e2_w, ws+f_wt_e2, 64, 128, 16);
  k_pack<<<(147456+255)/256, T, 0, stream>>>(e3_w, ws+f_wt_e3, 128, 128, 9);
  k_pack<<<(36864+255)/256, T, 0, stream>>>(er1a_w, ws+f_wt_ra1, 128, 32, 9);
  k_pack<<<(4096+255)/256, T, 0, stream>>>(er1b_w, ws+f_wt_rb1, 32, 128, 1);
  k_pack<<<(36864+255)/256, T, 0, stream>>>(er2a_w, ws+f_wt_ra2, 128, 32, 9);
  k_pack<<<(4096+255)/256, T, 0, stream>>>(er2b_w, ws+f_wt_rb2, 32, 128, 1);
  k_pack<<<(8192+255)/256, T, 0, stream>>>(ep_w, ws+f_wt_ep, 128, 64, 1);
  k_pack_d1<<<(73728+255)/256, T, 0, stream>>>(d1_w, ws+f_wt_d1);
  k_pack<<<(36864+255)/256, T, 0, stream>>>(dr1a_w, ws+f_wt_da1, 128, 32, 9);
  k_pack<<<(4096+255)/256, T, 0, stream>>>(dr1b_w, ws+f_wt_db1, 32, 128, 1);
  k_pack<<<(36864+255)/256, T, 0, stream>>>(dr2a_w, ws+f_wt_da2, 128, 32, 9);
  k_pack<<<(4096+255)/256, T, 0, stream>>>(dr2b_w, ws+f_wt_db2, 32, 128, 1);
  k_pack_d2p<<<512, T, 0, stream>>>(d2_w, ws+f_wt_d2);
  k_pack_d3p<<<20, T, 0, stream>>>(d3_w, ws+f_wt_d3);
  k_cb2<<<8, 64, 0, stream>>>(cb, ws+f_cb2);

  // front
  k_taylor<<<5120, T, 0, stream>>>(x, tc, t, ws+f_gpart);
  k_chw<<<1, 128, 0, stream>>>(ws+f_gpart, ca_w1, ca_b1, ca_w2, ca_b2, bn_g, bn_b, bn_m, bn_v,
                               ws+f_chw, ws+f_bnsb);
  k_spin<<<dim3(256,16), T, 0, stream>>>(t, ws+f_chw, spm, spx);
  k_sa<<<dim3(256,16), T, 0, stream>>>(spm, spx, sa_w, sa_b, samap);
  k_mix<<<dim3(256,16), T, 0, stream>>>(t, samap, mix_w, mix_b, ws+f_bnsb, t3, mnmx);
  k_norm<<<12288, T, 0, stream>>>(t3, mnmx);

  // encoder
  convk16<<<dim3(64,4,16), T, 0, stream>>>(t3, ws+f_wt_e1, e1_b, h1);
  // e2: ROWS=4, ci unroll 4 (round-34: grid-limited 4 waves/SIMD -> VGPR free to 128)
  conv8s2<64,128,4,false,true><<<dim3(4,16,16), T, 0, stream>>>(h1, ws+f_wt_e2, e2_b, h2);
  // e3: ROWS=4, U=4
  conv8<128,128,3,3,1,1,4,4,false,false,false><<<dim3(4,16,16), T, 0, stream>>>(h2, ws+f_wt_e3, e3_b, nullptr, h3, 4096,64,1,0);
  // res 3x3 128->32: ROWS=1 -> 1024 blocks = 4/CU
  conv8<128,32,3,3,1,1,1,2,true,true,false><<<dim3(16,4,16), T, 0, stream>>>(h3, ws+f_wt_ra1, er1a_b, nullptr, rtmp, 4096,64,1,0);
  conv8<32,128,1,1,0,0,2,4,false,false,true><<<dim3(8,16,16), T, 0, stream>>>(rtmp, ws+f_wt_rb1, er1b_b, h3, h3, 4096,64,1,0);
  conv8<128,32,3,3,1,1,1,2,true,true,false><<<dim3(16,4,16), T, 0, stream>>>(h3, ws+f_wt_ra2, er2a_b, nullptr, rtmp, 4096,64,1,0);
  conv8<32,128,1,1,0,0,2,4,false,false,true><<<dim3(8,16,16), T, 0, stream>>>(rtmp, ws+f_wt_rb2, er2b_b, h3, h3, 4096,64,1,0);
  conv8<128,64,1,1,0,0,2,4,true,false,false><<<dim3(8,8,16), T, 0, stream>>>(h3, ws+f_wt_ep, ep_b, nullptr, zenc, 4096,64,1,0);

  // VQ: codebook split across 4 block-columns (coalescing preserved), then finalize pass
  k_vqscan<<<dim3(256,4), T, 0, stream>>>(zenc, cb, ws+f_cb2, vqkeys);
  k_vqfin<<<256, T, 0, stream>>>(zenc, cb, vqkeys, idx, ws+f_lossp, ws+f_counts);
  k_finalize<<<1, 512, 0, stream>>>(ws+f_counts, ws+f_lossp, out);
  k_gather<<<16384, T, 0, stream>>>(cb, idx, zq);

  // decoder
  // d1: ROWS=4, U=4
  conv8<64,128,3,3,1,1,4,4,false,false,false><<<dim3(4,16,16), T, 0, stream>>>(zq, ws+f_wt_d1, d1_b, nullptr, dh1, 4096,64,1,0);
  conv8<128,32,3,3,1,1,1,2,true,true,false><<<dim3(16,4,16), T, 0, stream>>>(dh1, ws+f_wt_da1, dr1a_b, nullptr, rtmp, 4096,64,1,0);
  conv8<32,128,1,1,0,0,2,4,false,false,true><<<dim3(8,16,16), T, 0, stream>>>(rtmp, ws+f_wt_db1, dr1b_b, dh1, dh1, 4096,64,1,0);
  conv8<128,32,3,3,1,1,1,2,true,true,false><<<dim3(16,4,16), T, 0, stream>>>(dh1, ws+f_wt_da2, dr2a_b, nullptr, rtmp, 4096,64,1,0);
  conv8<32,128,1,1,0,0,2,4,false,false,true><<<dim3(8,16,16), T, 0, stream>>>(rtmp, ws+f_wt_db2, dr2b_b, dh1, dh1, 4096,64,1,0);
  // d2: both px parities per block, ROWS=4 (intensity rule); grid 1024 = 4/CU
  convd2p<<<dim3(4,16,16), T, 0, stream>>>(dh1, ws+f_wt_d2, d2_b, dh2);
  // d3: all 4 parities fused in one 1024-block launch (parity = blockIdx.y)
  convd3<<<dim3(16,4,16), T, 0, stream>>>(dh2, ws+f_wt_d3, d3_b, out);
}

// Round 35
// 2016.681 us; speedup vs baseline: 1.2355x; 1.2355x over previous
//
#include <hip/hip_runtime.h>

#define DEV __device__ __forceinline__

typedef float f4_t __attribute__((ext_vector_type(4)));

DEV unsigned f2ord(float f){ unsigned u=__float_as_uint(f); return (u&0x80000000u)? ~u : (u|0x80000000u); }
DEV float ord2f(unsigned o){ unsigned u=(o&0x80000000u)? (o&0x7FFFFFFFu) : ~o; return __uint_as_float(u); }
DEV float wsum(float v){ for(int o=32;o;o>>=1) v+=__shfl_down(v,o,64); return v; }
DEV float wminr(float v){ for(int o=32;o;o>>=1) v=fminf(v,__shfl_down(v,o,64)); return v; }
DEV float wmaxr(float v){ for(int o=32;o;o>>=1) v=fmaxf(v,__shfl_down(v,o,64)); return v; }

// ---------------- init ----------------
__global__ void k_init(float* counts, unsigned* mnmx){
  int i = threadIdx.x;
  if (i < 512) counts[i] = 0.f;
  if (i < 48) mnmx[i] = 0xFFFFFFFFu;
  if (i >= 64 && i < 112) mnmx[i-64+48] = 0u;
}
__global__ void k_initvq(unsigned long long* keys){
  int i = blockIdx.x*256 + threadIdx.x;
  keys[i] = ~0ull;
}

// ---------------- front ----------------
__global__ __launch_bounds__(256) void k_taylor(const float* __restrict__ x, const float* __restrict__ tc,
                                                float* __restrict__ t, float* __restrict__ gpart){
  int blk = blockIdx.x;
  int bc = blk >> 6, chunk = blk & 63;
  float k0=tc[0], k1=tc[1], k2=tc[2]*0.5f, k3=tc[3]*(1.f/6.f), k4=tc[4]*(1.f/24.f);
  size_t base = (size_t)bc*65536 + (size_t)chunk*1024;
  float s = 0.f;
  #pragma unroll
  for (int j=0;j<4;j++){
    size_t i = base + threadIdx.x + j*256;
    float xv = x[i];
    float tv = k0 + xv*(k1 + xv*(k2 + xv*(k3 + xv*k4)));
    t[i] = tv; s += tv;
  }
  s = wsum(s);
  __shared__ float ws4[4];
  int lane = threadIdx.x & 63, wv = threadIdx.x >> 6;
  if (lane==0) ws4[wv]=s;
  __syncthreads();
  if (threadIdx.x==0) gpart[blk] = ws4[0]+ws4[1]+ws4[2]+ws4[3];
}

__global__ void k_chw(const float* __restrict__ gpart, const float* __restrict__ w1, const float* __restrict__ b1,
                      const float* __restrict__ w2, const float* __restrict__ b2,
                      const float* __restrict__ bng, const float* __restrict__ bnb,
                      const float* __restrict__ bnm, const float* __restrict__ bnv,
                      float* __restrict__ chw, float* __restrict__ bnsb){
  __shared__ float g[80];
  int tid = threadIdx.x; // 128
  if (tid < 80){
    float s = 0.f;
    for (int j=0;j<64;j++) s += gpart[tid*64+j];
    g[tid] = s * (1.f/65536.f);
  }
  __syncthreads();
  if (tid < 16){
    int b = tid;
    float h[4];
    for (int j=0;j<4;j++){
      float a = b1[j];
      for (int c=0;c<5;c++) a += g[b*5+c]*w1[j*5+c];
      h[j] = fmaxf(a, 0.f);
    }
    for (int c=0;c<5;c++){
      float a = b2[c];
      for (int j=0;j<4;j++) a += h[j]*w2[c*4+j];
      chw[b*5+c] = 1.f/(1.f+expf(-a));
    }
  } else if (tid >= 32 && tid < 35){
    int c = tid-32;
    float sc = bng[c] / sqrtf(bnv[c] + 1e-5f);
    bnsb[c] = sc;
    bnsb[4+c] = bnb[c] - bnm[c]*sc;
  }
}

__global__ __launch_bounds__(256) void k_spin(float* __restrict__ t, const float* __restrict__ chw,
                                              float* __restrict__ spm, float* __restrict__ spx){
  int b = blockIdx.y;
  int p = blockIdx.x*256 + threadIdx.x;
  size_t base = ((size_t)b*5)*65536 + p;
  float vs=0.f, vmax=-3.0e38f;
  #pragma unroll
  for (int c=0;c<5;c++){
    float v = t[base + (size_t)c*65536] * chw[b*5+c];
    t[base + (size_t)c*65536] = v;
    vs += v; vmax = fmaxf(vmax, v);
  }
  spm[(size_t)b*65536+p] = vs*0.2f;
  spx[(size_t)b*65536+p] = vmax;
}

__global__ __launch_bounds__(256) void k_sa(const float* __restrict__ spm, const float* __restrict__ spx,
                                            const float* __restrict__ w, const float* __restrict__ bias,
                                            float* __restrict__ samap){
  int b = blockIdx.y;
  int p = blockIdx.x*256 + threadIdx.x;
  int y0 = p >> 8, x0 = p & 255;
  float acc = bias[0];
  const float* sp0 = spm + (size_t)b*65536;
  const float* sp1 = spx + (size_t)b*65536;
  #pragma unroll
  for (int ky=0;ky<7;ky++){
    int iy = y0 - 3 + ky;
    if ((unsigned)iy >= 256u) continue;
    #pragma unroll
    for (int kx=0;kx<7;kx++){
      int ix = x0 - 3 + kx;
      if ((unsigned)ix >= 256u) continue;
      acc += sp0[iy*256+ix] * w[ky*7+kx] + sp1[iy*256+ix] * w[49+ky*7+kx];
    }
  }
  samap[(size_t)b*65536+p] = 1.f/(1.f+expf(-acc));
}

__global__ __launch_bounds__(256) void k_mix(const float* __restrict__ t, const float* __restrict__ samap,
                                             const float* __restrict__ mw, const float* __restrict__ mb,
                                             const float* __restrict__ bnsb, float* __restrict__ t3,
                                             unsigned* __restrict__ mnmx){
  int b = blockIdx.y;
  int p = blockIdx.x*256 + threadIdx.x;
  float s = samap[(size_t)b*65536+p];
  float v[5];
  #pragma unroll
  for (int c=0;c<5;c++) v[c] = t[((size_t)b*5+c)*65536+p] * s;
  float mn[3], mx[3];
  #pragma unroll
  for (int co=0;co<3;co++){
    float a = mb[co];
    #pragma unroll
    for (int ci=0;ci<5;ci++) a += v[ci]*mw[co*5+ci];
    a = a*bnsb[co] + bnsb[4+co];
    a = (a >= 0.f) ? a : 0.1f*a;
    t3[((size_t)b*3+co)*65536+p] = a;
    mn[co]=a; mx[co]=a;
  }
  __shared__ float smn[3][4], smx[3][4];
  int lane = threadIdx.x & 63, wv = threadIdx.x >> 6;
  #pragma unroll
  for (int co=0;co<3;co++){
    float lmn = wminr(mn[co]);
    float lmx = wmaxr(mx[co]);
    if (lane==0){ smn[co][wv]=lmn; smx[co][wv]=lmx; }
  }
  __syncthreads();
  if (threadIdx.x==0){
    #pragma unroll
    for (int co=0;co<3;co++){
      float m0 = fminf(fminf(smn[co][0],smn[co][1]),fminf(smn[co][2],smn[co][3]));
      float m1 = fmaxf(fmaxf(smx[co][0],smx[co][1]),fmaxf(smx[co][2],smx[co][3]));
      atomicMin(&mnmx[b*3+co], f2ord(m0));
      atomicMax(&mnmx[48+b*3+co], f2ord(m1));
    }
  }
}

__global__ __launch_bounds__(256) void k_norm(float* __restrict__ t3, const unsigned* __restrict__ mnmx){
  int i = blockIdx.x*256 + threadIdx.x;
  int bc = i >> 16;
  float mn = ord2f(mnmx[bc]);
  float mx = ord2f(mnmx[48+bc]);
  t3[i] = (t3[i] - mn) / (mx - mn + 1e-4f);
}

// ---------------- weight packing ----------------
__global__ void k_pack(const float* __restrict__ w, float* __restrict__ wt, int CIN, int COUT, int KHW){
  int i = blockIdx.x*256 + threadIdx.x;
  int total = CIN*COUT*KHW;
  if (i >= total) return;
  int co = i % COUT; int tt = i / COUT;
  int ci = tt / KHW, k = tt % KHW;
  wt[i] = w[(co*CIN + ci)*KHW + k];
}
__global__ void k_pack_d1(const float* __restrict__ w, float* __restrict__ wt){
  int i = blockIdx.x*256 + threadIdx.x; // 64*9*128
  if (i >= 64*9*128) return;
  int co = i & 127; int tt = i >> 7;
  int ci = tt / 9, k = tt % 9;
  int ky = k/3, kx = k%3;
  wt[i] = w[(ci*128 + co)*9 + (2-ky)*3 + (2-kx)];
}
// d2 per-parity pack: out[par][(ci*4 + kyp*2+kxp)*64 + co], ky = 3-py-2*kyp, kx = 3-px-2*kxp
__global__ void k_pack_d2p(const float* __restrict__ w, float* __restrict__ wt){
  int i = blockIdx.x*256 + threadIdx.x; // 4*128*4*64 = 131072
  if (i >= 131072) return;
  int co = i & 63; int t = i >> 6;
  int kk = t & 3; int t2 = t >> 2;
  int ci = t2 & 127; int par = t2 >> 7;
  int py = par >> 1, px = par & 1;
  int kyp = kk >> 1, kxp = kk & 1;
  int ky = 3 - py - 2*kyp;
  int kx = 3 - px - 2*kxp;
  wt[i] = w[((size_t)ci*64 + co)*16 + ky*4 + kx];
}
// d3 per-parity pack: out[par][(ci*4 + kyp*2+kxp)*5 + co], same tap algebra as d2p; COUT=5
__global__ void k_pack_d3p(const float* __restrict__ w, float* __restrict__ wt){
  int i = blockIdx.x*256 + threadIdx.x; // 4*64*4*5 = 5120
  if (i >= 5120) return;
  int co = i % 5; int t = i / 5;
  int kk = t & 3; int t2 = t >> 2;
  int ci = t2 & 63; int par = t2 >> 6;
  int py = par >> 1, px = par & 1;
  int kyp = kk >> 1, kxp = kk & 1;
  int ky = 3 - py - 2*kyp;
  int kx = 3 - px - 2*kxp;
  wt[i] = w[((size_t)ci*5 + co)*16 + ky*4 + kx];
}
__global__ void k_cb2(const float* __restrict__ cb, float* __restrict__ cb2){
  int c = blockIdx.x*64 + threadIdx.x;
  if (c >= 512) return;
  float s=0.f;
  for (int d=0; d<64; d++){ float v = cb[c*64+d]; s += v*v; }
  cb2[c] = s;
}

// ---------------- e1 direct conv, 16 co per thread ----------------
__global__ __launch_bounds__(256) void convk16(const float* __restrict__ x, const float* __restrict__ wt,
                                               const float* __restrict__ bias, float* __restrict__ y){
  int p = blockIdx.x*256 + threadIdx.x;   // 16384 output pixels (128x128)
  int oy = p >> 7, ox = p & 127;
  int co = blockIdx.y*16;
  int n  = blockIdx.z;
  const float* xn = x + (size_t)n*3*65536;
  f4_t a0 = *(const f4_t*)&bias[co];
  f4_t a1 = *(const f4_t*)&bias[co+4];
  f4_t a2 = *(const f4_t*)&bias[co+8];
  f4_t a3 = *(const f4_t*)&bias[co+12];
  #pragma unroll
  for (int ky=0; ky<4; ky++){
    int iy = oy*2 - 1 + ky;
    bool rok = (unsigned)iy < 256u;
    #pragma unroll
    for (int kx=0; kx<4; kx++){
      int ix = ox*2 - 1 + kx;
      bool ok = rok && ((unsigned)ix < 256u);
      const float* xp = xn + (size_t)iy*256 + ix;
      const float* wp = wt + (ky*4 + kx)*64 + co;
      #pragma unroll
      for (int ci=0; ci<3; ci++){
        float v = ok ? xp[ci*65536] : 0.f;
        const f4_t w0 = *(const f4_t*)(wp + ci*1024);
        const f4_t w1 = *(const f4_t*)(wp + ci*1024 + 4);
        const f4_t w2 = *(const f4_t*)(wp + ci*1024 + 8);
        const f4_t w3 = *(const f4_t*)(wp + ci*1024 + 12);
        a0 += v*w0; a1 += v*w1; a2 += v*w2; a3 += v*w3;
      }
    }
  }
  size_t yb = ((size_t)n*64 + co)*16384 + p;
  #pragma unroll
  for (int j=0;j<16;j++){
    float av = (j<4) ? ((const float*)&a0)[j]
             : (j<8) ? ((const float*)&a1)[j-4]
             : (j<12)? ((const float*)&a2)[j-8]
             :         ((const float*)&a3)[j-12];
    y[yb + (size_t)j*16384] = fmaxf(av, 0.f);
  }
}

// ---------------- tiled conv v2: thread = ROWS rows x 8 co, per-instantiation unroll U ------
template<int CIN,int COUT,int KH,int KW,int PY,int PX,int ROWS,int U,bool RIN,bool ROUT,bool ADD>
__global__ __launch_bounds__(256) void conv8(const float* __restrict__ x, const float* __restrict__ wt,
                                             const float* __restrict__ bias, const float* __restrict__ res,
                                             float* __restrict__ y,
                                             int plane, int rstr, int cstr, int obase){
  constexpr int KHW = KH*KW;
  constexpr int NR  = KH + ROWS - 1;
  int tid = threadIdx.x;
  int cob = blockIdx.y*8;
  int ox  = tid & 63;
  int oy0 = blockIdx.x*(4*ROWS) + (tid>>6)*ROWS;
  int n   = blockIdx.z;
  const float* xn = x + (size_t)n*CIN*4096;
  f4_t b0 = *(const f4_t*)&bias[cob];
  f4_t b1 = *(const f4_t*)&bias[cob+4];
  f4_t acc0[ROWS], acc1[ROWS];
  #pragma unroll
  for (int r=0;r<ROWS;r++){ acc0[r] = b0; acc1[r] = b1; }

  for (int cb0=0; cb0<CIN; cb0+=U){
    #pragma unroll
    for (int u=0; u<U; u++){
      int ci = cb0 + u;
      const float* xc = xn + (size_t)ci*4096;
      float c0[NR], cl[NR], cr[NR];
      #pragma unroll
      for (int rr=0; rr<NR; rr++){
        int iy = oy0 - PY + rr;
        bool vr = (unsigned)iy < 64u;
        float v = vr ? xc[iy*64 + ox] : 0.f;
        if (RIN) v = fmaxf(v, 0.f);
        c0[rr] = v;
      }
      #pragma unroll
      for (int rr=0; rr<NR; rr++){
        if (KW == 3){
          float l = __shfl_up(c0[rr], 1, 64);   if (ox==0)  l = 0.f;
          float g = __shfl_down(c0[rr], 1, 64); if (ox==63) g = 0.f;
          cl[rr] = l; cr[rr] = g;
        } else if (KW == 2){
          float s;
          if (PX == 1){ s = __shfl_up(c0[rr], 1, 64);   if (ox==0)  s = 0.f; }
          else        { s = __shfl_down(c0[rr], 1, 64); if (ox==63) s = 0.f; }
          cl[rr] = s;
        }
      }
      const float* wci = wt + (size_t)ci*KHW*COUT + cob;
      #pragma unroll
      for (int ky=0; ky<KH; ky++){
        #pragma unroll
        for (int kx=0; kx<KW; kx++){
          f4_t w0 = *(const f4_t*)(wci + (ky*KW + kx)*COUT);
          f4_t w1 = *(const f4_t*)(wci + (ky*KW + kx)*COUT + 4);
          #pragma unroll
          for (int r=0; r<ROWS; r++){
            int rr = r + ky;
            float v;
            if (KW == 1)      v = c0[rr];
            else if (KW == 3) v = (kx==0) ? cl[rr] : ((kx==1) ? c0[rr] : cr[rr]);
            else              v = (kx==PX) ? c0[rr] : cl[rr];
            acc0[r] += v * w0;
            acc1[r] += v * w1;
          }
        }
      }
    }
  }

  #pragma unroll
  for (int r=0;r<ROWS;r++){
    size_t base = ((size_t)n*COUT + cob)*plane + (size_t)(oy0+r)*rstr + obase + ox*cstr;
    #pragma unroll
    for (int j=0;j<8;j++){
      float a = (j<4) ? ((const float*)&acc0[r])[j] : ((const float*)&acc1[r])[j-4];
      if (ROUT) a = fmaxf(a, 0.f);
      if (ADD)  a += res[base + (size_t)j*plane];
      y[base + (size_t)j*plane] = a;
    }
  }
}

// ---------------- tiled conv v2: e2 (128x128 -> 64x64, k=4 s=2 p=1), ROWS rows x 8 co ----------
template<int CIN,int COUT,int ROWS,bool RIN,bool ROUT>
__global__ __launch_bounds__(256) void conv8s2(const float* __restrict__ x, const float* __restrict__ wt,
                                               const float* __restrict__ bias, float* __restrict__ y){
  constexpr int NRI = 2*ROWS + 2;
  int tid = threadIdx.x;
  int cob = blockIdx.y*8;
  int ox  = tid & 63;
  int oy0 = blockIdx.x*(4*ROWS) + (tid>>6)*ROWS;
  int n   = blockIdx.z;
  const float* xn = x + (size_t)n*CIN*16384;
  f4_t b0 = *(const f4_t*)&bias[cob];
  f4_t b1 = *(const f4_t*)&bias[cob+4];
  f4_t acc0[ROWS], acc1[ROWS];
  #pragma unroll
  for (int r=0;r<ROWS;r++){ acc0[r] = b0; acc1[r] = b1; }

  #pragma unroll 2
  for (int ci=0; ci<CIN; ci++){
    const float* xc = xn + (size_t)ci*16384;
    float A[NRI], Bb[NRI], L[NRI], R[NRI];
    #pragma unroll
    for (int rr=0; rr<NRI; rr++){
      int iy = 2*oy0 - 1 + rr;
      bool vr = (unsigned)iy < 128u;
      float a = 0.f, b = 0.f;
      if (vr){
        float2 ab = *(const float2*)(xc + iy*128 + 2*ox);
        a = ab.x; b = ab.y;
      }
      if (RIN){ a = fmaxf(a,0.f); b = fmaxf(b,0.f); }
      A[rr] = a; Bb[rr] = b;
    }
    #pragma unroll
    for (int rr=0; rr<NRI; rr++){
      float l = __shfl_up(Bb[rr], 1, 64);  if (ox==0)  l = 0.f;   // ix = 2ox-1
      float g = __shfl_down(A[rr], 1, 64); if (ox==63) g = 0.f;   // ix = 2ox+2
      L[rr] = l; R[rr] = g;
    }
    const float* wci = wt + (size_t)ci*16*COUT + cob;
    #pragma unroll
    for (int ky=0; ky<4; ky++){
      #pragma unroll
      for (int kx=0; kx<4; kx++){
        f4_t w0 = *(const f4_t*)(wci + (ky*4 + kx)*COUT);
        f4_t w1 = *(const f4_t*)(wci + (ky*4 + kx)*COUT + 4);
        #pragma unroll
        for (int r=0; r<ROWS; r++){
          int rr = 2*r + ky;
          float v = (kx==0) ? L[rr] : ((kx==1) ? A[rr] : ((kx==2) ? Bb[rr] : R[rr]));
          acc0[r] += v * w0;
          acc1[r] += v * w1;
        }
      }
    }
  }

  #pragma unroll
  for (int r=0;r<ROWS;r++){
    size_t base = ((size_t)n*COUT + cob)*4096 + (size_t)(oy0+r)*64 + ox;
    #pragma unroll
    for (int j=0;j<8;j++){
      float a = (j<4) ? ((const float*)&acc0[r])[j] : ((const float*)&acc1[r])[j-4];
      if (ROUT) a = fmaxf(a, 0.f);
      y[base + (size_t)j*4096] = a;
    }
  }
}

// ---------------- d2 ConvTranspose: BOTH px parities per block, ROWS=4 ----------
__global__ __launch_bounds__(256) void convd2p(const float* __restrict__ x, const float* __restrict__ wt,
                                               const float* __restrict__ bias, float* __restrict__ y){
  constexpr int ROWS = 4;
  constexpr int NR   = ROWS + 1;   // KH=2
  int py   = blockIdx.y >> 3;
  int cob  = (blockIdx.y & 7)*8;
  int PY   = 1 - py;
  const float* wpA = wt + (size_t)(py*2    )*32768;   // px=0 parity
  const float* wpB = wt + (size_t)(py*2 + 1)*32768;   // px=1 parity
  int tid = threadIdx.x;
  int ox  = tid & 63;
  int oy0 = blockIdx.x*(4*ROWS) + (tid>>6)*ROWS;
  int n   = blockIdx.z;
  const float* xn = x + (size_t)n*128*4096;
  f4_t b0 = *(const f4_t*)&bias[cob];
  f4_t b1 = *(const f4_t*)&bias[cob+4];
  f4_t aA0[ROWS], aA1[ROWS], aB0[ROWS], aB1[ROWS];
  #pragma unroll
  for (int r=0;r<ROWS;r++){ aA0[r]=b0; aA1[r]=b1; aB0[r]=b0; aB1[r]=b1; }

  #pragma unroll 2
  for (int ci=0; ci<128; ci++){
    const float* xc = xn + (size_t)ci*4096;
    float c0[NR], cl[NR], cr[NR];
    #pragma unroll
    for (int rr=0; rr<NR; rr++){
      int iy = oy0 - PY + rr;
      bool vr = (unsigned)iy < 64u;
      float v = vr ? xc[iy*64 + ox] : 0.f;
      c0[rr] = fmaxf(v, 0.f);                 // RIN (input is pre-ReLU dh1)
    }
    #pragma unroll
    for (int rr=0; rr<NR; rr++){
      float su = __shfl_up(c0[rr], 1, 64);   if (ox==0)  su = 0.f;
      float sd = __shfl_down(c0[rr], 1, 64); if (ox==63) sd = 0.f;
      cl[rr] = su; cr[rr] = sd;
    }
    const float* wciA = wpA + (size_t)ci*256 + cob;
    const float* wciB = wpB + (size_t)ci*256 + cob;
    #pragma unroll
    for (int ky=0; ky<2; ky++){
      #pragma unroll
      for (int kx=0; kx<2; kx++){
        f4_t w0 = *(const f4_t*)(wciA + (ky*2 + kx)*64);
        f4_t w1 = *(const f4_t*)(wciA + (ky*2 + kx)*64 + 4);
        #pragma unroll
        for (int r=0; r<ROWS; r++){
          int rr = r + ky;
          float v = (kx == 1) ? c0[rr] : cl[rr];
          aA0[r] += v * w0;
          aA1[r] += v * w1;
        }
      }
    }
    #pragma unroll
    for (int ky=0; ky<2; ky++){
      #pragma unroll
      for (int kx=0; kx<2; kx++){
        f4_t w0 = *(const f4_t*)(wciB + (ky*2 + kx)*64);
        f4_t w1 = *(const f4_t*)(wciB + (ky*2 + kx)*64 + 4);
        #pragma unroll
        for (int r=0; r<ROWS; r++){
          int rr = r + ky;
          float v = (kx == 0) ? c0[rr] : cr[rr];
          aB0[r] += v * w0;
          aB1[r] += v * w1;
        }
      }
    }
  }

  #pragma unroll
  for (int r=0;r<ROWS;r++){
    size_t rowb = ((size_t)n*64 + cob)*16384 + (size_t)(oy0+r)*256 + py*128 + ox*2;
    #pragma unroll
    for (int j=0;j<8;j++){
      float a = (j<4) ? ((const float*)&aA0[r])[j] : ((const float*)&aA1[r])[j-4];
      float b = (j<4) ? ((const float*)&aB0[r])[j] : ((const float*)&aB1[r])[j-4];
      float2 v2; v2.x = fmaxf(a, 0.f); v2.y = fmaxf(b, 0.f);   // ROUT
      *(float2*)&y[rowb + (size_t)j*16384] = v2;
    }
  }
}

// ---------------- d3 ConvTranspose k=4 s=2 p=1, ALL 4 parities in one launch ----------------
__global__ __launch_bounds__(256) void convd3(const float* __restrict__ x, const float* __restrict__ wt,
                                              const float* __restrict__ bias, float* __restrict__ y){
  constexpr int ROWS = 2;
  constexpr int NRI  = ROWS + 1;
  int par  = blockIdx.y;
  int py   = par >> 1, px = par & 1;
  int PY   = 1 - py,  PX = 1 - px;
  const float* wpar = wt + par*1280;
  int tid  = threadIdx.x;
  int lane = tid & 63, wv = tid >> 6;
  int oy0  = blockIdx.x*(4*ROWS) + wv*ROWS;
  int n    = blockIdx.z;
  const float* xn = x + (size_t)n*64*16384;
  float b[5];
  #pragma unroll
  for (int j=0;j<5;j++) b[j] = bias[j];
  float acc[ROWS][2][5];
  #pragma unroll
  for (int r=0;r<ROWS;r++)
    #pragma unroll
    for (int c=0;c<2;c++)
      #pragma unroll
      for (int j=0;j<5;j++) acc[r][c][j] = b[j];

  #pragma unroll 2
  for (int ci=0; ci<64; ci++){
    const float* xc = xn + (size_t)ci*16384;
    float A[NRI], Bv[NRI], S[NRI];
    #pragma unroll
    for (int rr=0; rr<NRI; rr++){
      int iy = oy0 - PY + rr;
      float a = 0.f, bb = 0.f;
      if ((unsigned)iy < 128u){
        float2 ab = *(const float2*)(xc + iy*128 + 2*lane);
        a = ab.x; bb = ab.y;
      }
      A[rr] = a; Bv[rr] = bb;
    }
    if (PX == 1){
      #pragma unroll
      for (int rr=0; rr<NRI; rr++){
        float l = __shfl_up(Bv[rr], 1, 64); if (lane==0) l = 0.f;
        S[rr] = l;                       // L: ix = 2*lane-1
      }
    } else {
      #pragma unroll
      for (int rr=0; rr<NRI; rr++){
        float g = __shfl_down(A[rr], 1, 64); if (lane==63) g = 0.f;
        S[rr] = g;                       // R: ix = 2*lane+2
      }
    }
    const float* wci = wpar + ci*20;
    #pragma unroll
    for (int kyp=0; kyp<2; kyp++){
      #pragma unroll
      for (int kxp=0; kxp<2; kxp++){
        const float* wp = wci + (kyp*2 + kxp)*5;
        #pragma unroll
        for (int r=0; r<ROWS; r++){
          int rr = r + kyp;
          float v0, v1;
          if (PX == 1){ v0 = (kxp==0) ? S[rr]  : A[rr];  v1 = (kxp==0) ? A[rr]  : Bv[rr]; }
          else        { v0 = (kxp==0) ? A[rr]  : Bv[rr]; v1 = (kxp==0) ? Bv[rr] : S[rr];  }
          #pragma unroll
          for (int j=0;j<5;j++){
            acc[r][0][j] = fmaf(v0, wp[j], acc[r][0][j]);
            acc[r][1][j] = fmaf(v1, wp[j], acc[r][1][j]);
          }
        }
      }
    }
  }

  #pragma unroll
  for (int r=0;r<ROWS;r++){
    size_t rowb = (size_t)n*5*65536 + (size_t)(2*(oy0+r)+py)*256;
    #pragma unroll
    for (int j=0;j<5;j++){
      y[rowb + (size_t)j*65536 + 4*lane + px]     = acc[r][0][j];
      y[rowb + (size_t)j*65536 + 4*lane + 2 + px] = acc[r][1][j];
    }
  }
}

// ---------------- VQ: codebook split across BLOCKS, rows stay 1/thread (round-26) ----------
__global__ __launch_bounds__(256) void k_vqscan(const float* __restrict__ zenc, const float* __restrict__ cb,
                                                const float* __restrict__ cb2,
                                                unsigned long long* __restrict__ keys){
  int r = blockIdx.x*256 + threadIdx.x;
  int q = blockIdx.y;
  int b = r >> 12, p = r & 4095;
  const float* zp = zenc + ((size_t)b*64)*4096 + p;
  float z[64];
  float z2 = 0.f;
  #pragma unroll
  for (int d=0; d<64; d++){ z[d] = zp[(size_t)d*4096]; z2 += z[d]*z[d]; }
  float best = 3.4e38f; int bi = 0;
  int cbeg = q*128;
  for (int c=cbeg; c<cbeg+128; c+=4){
    float dot0=0.f, dot1=0.f, dot2=0.f, dot3=0.f;
    const float* c0 = cb + c*64;
    #pragma unroll
    for (int d=0; d<64; d++){
      float zd = z[d];
      dot0 = fmaf(zd, c0[d],     dot0);
      dot1 = fmaf(zd, c0[64+d],  dot1);
      dot2 = fmaf(zd, c0[128+d], dot2);
      dot3 = fmaf(zd, c0[192+d], dot3);
    }
    float d0 = (z2 + cb2[c])   - 2.f*dot0;
    float d1 = (z2 + cb2[c+1]) - 2.f*dot1;
    float d2 = (z2 + cb2[c+2]) - 2.f*dot2;
    float d3 = (z2 + cb2[c+3]) - 2.f*dot3;
    if (d0 < best){ best = d0; bi = c; }
    if (d1 < best){ best = d1; bi = c+1; }
    if (d2 < best){ best = d2; bi = c+2; }
    if (d3 < best){ best = d3; bi = c+3; }
  }
  unsigned long long key = ((unsigned long long)f2ord(best) << 32) | (unsigned long long)(unsigned)bi;
  atomicMin(&keys[r], key);
}

__global__ __launch_bounds__(256) void k_vqfin(const float* __restrict__ zenc, const float* __restrict__ cb,
                                               const unsigned long long* __restrict__ keys,
                                               int* __restrict__ idx, float* __restrict__ lossp,
                                               float* __restrict__ counts){
  int r = blockIdx.x*256 + threadIdx.x;
  int b = r >> 12, p = r & 4095;
  int bi = (int)(keys[r] & 0xFFFFFFFFull);
  idx[r] = bi;
  const float* zp = zenc + ((size_t)b*64)*4096 + p;
  const float* cbest = cb + bi*64;
  float l = 0.f;
  #pragma unroll
  for (int d=0; d<64; d++){ float df = zp[(size_t)d*4096] - cbest[d]; l = fmaf(df,df,l); }
  l = wsum(l);
  __shared__ float ls[4];
  __shared__ int hist[512];
  int lane = threadIdx.x & 63, wv = threadIdx.x >> 6;
  if (lane==0) ls[wv] = l;
  for (int i=threadIdx.x; i<512; i+=256) hist[i]=0;
  __syncthreads();
  atomicAdd(&hist[bi], 1);
  if (threadIdx.x==0) lossp[blockIdx.x] = ls[0]+ls[1]+ls[2]+ls[3];
  __syncthreads();
  for (int i=threadIdx.x; i<512; i+=256){
    int h = hist[i];
    if (h) atomicAdd(&counts[i], (float)h);
  }
}

__global__ void k_finalize(const float* __restrict__ counts, const float* __restrict__ lossp,
                           float* __restrict__ out){
  __shared__ float sl[8], st[8];
  int tid = threadIdx.x; // 512
  int lane = tid & 63, wv = tid >> 6;
  float lp = (tid < 256) ? lossp[tid] : 0.f;
  lp = wsum(lp);
  if (lane==0) sl[wv] = lp;
  float pr = counts[tid] * (1.f/65536.f);
  float term = pr * logf(pr + 1e-10f);
  term = wsum(term);
  if (lane==0) st[wv] = term;
  __syncthreads();
  if (tid==0){
    float L=0.f, S=0.f;
    for (int i=0;i<8;i++){ L += sl[i]; S += st[i]; }
    out[5242880] = L * 0.25f / (65536.f*64.f);
    out[5242881] = expf(-S);
  }
}

__global__ __launch_bounds__(256) void k_gather(const float* __restrict__ cb, const int* __restrict__ idx,
                                                float* __restrict__ zq){
  int i = blockIdx.x*256 + threadIdx.x;
  int p = i & 4095;
  int d = (i >> 12) & 63;
  int b = i >> 18;
  zq[i] = cb[idx[(b<<12) + p]*64 + d];
}

// ---------------- launch ----------------
extern "C" void kernel_launch(void* const* d_in, const int* in_sizes, int n_in,
                              void* d_out, int out_size, void* d_ws, size_t ws_size,
                              hipStream_t stream){
  (void)in_sizes; (void)n_in; (void)out_size;
  const float* x     = (const float*)d_in[0];
  const float* tc    = (const float*)d_in[1];
  const float* ca_w1 = (const float*)d_in[2];
  const float* ca_b1 = (const float*)d_in[3];
  const float* ca_w2 = (const float*)d_in[4];
  const float* ca_b2 = (const float*)d_in[5];
  const float* sa_w  = (const float*)d_in[6];
  const float* sa_b  = (const float*)d_in[7];
  const float* mix_w = (const float*)d_in[8];
  const float* mix_b = (const float*)d_in[9];
  const float* bn_g  = (const float*)d_in[10];
  const float* bn_b  = (const float*)d_in[11];
  const float* bn_m  = (const float*)d_in[12];
  const float* bn_v  = (const float*)d_in[13];
  const float* e1_w  = (const float*)d_in[14];
  const float* e1_b  = (const float*)d_in[15];
  const float* e2_w  = (const float*)d_in[16];
  const float* e2_b  = (const float*)d_in[17];
  const float* e3_w  = (const float*)d_in[18];
  const float* e3_b  = (const float*)d_in[19];
  const float* er1a_w= (const float*)d_in[20];
  const float* er1a_b= (const float*)d_in[21];
  const float* er1b_w= (const float*)d_in[22];
  const float* er1b_b= (const float*)d_in[23];
  const float* er2a_w= (const float*)d_in[24];
  const float* er2a_b= (const float*)d_in[25];
  const float* er2b_w= (const float*)d_in[26];
  const float* er2b_b= (const float*)d_in[27];
  const float* ep_w  = (const float*)d_in[28];
  const float* ep_b  = (const float*)d_in[29];
  const float* cb    = (const float*)d_in[30];
  const float* d1_w  = (const float*)d_in[31];
  const float* d1_b  = (const float*)d_in[32];
  const float* dr1a_w= (const float*)d_in[33];
  const float* dr1a_b= (const float*)d_in[34];
  const float* dr1b_w= (const float*)d_in[35];
  const float* dr1b_b= (const float*)d_in[36];
  const float* dr2a_w= (const float*)d_in[37];
  const float* dr2a_b= (const float*)d_in[38];
  const float* dr2b_w= (const float*)d_in[39];
  const float* dr2b_b= (const float*)d_in[40];
  const float* d2_w  = (const float*)d_in[41];
  const float* d2_b  = (const float*)d_in[42];
  const float* d3_w  = (const float*)d_in[43];
  const float* d3_b  = (const float*)d_in[44];
  float* out = (float*)d_out;
  float* ws = (float*)d_ws;

  size_t o = 0;
  auto alloc = [&](size_t n){ size_t r = o; o += (n + 63) & ~63ull; return r; };
  size_t f_buf0 = alloc(16777216);  // h1 (16,64,128,128); later zq head, then d2 out
  size_t f_buf1 = alloc(8388608);   // h2 (16,128,64,64); later dh1
  size_t f_buf2 = alloc(8388608);   // h3
  size_t f_buf3 = alloc(5242880);   // t (16,5,256,256); later zenc (16,64,64,64)
  size_t f_buf4 = alloc(3145728);   // t3 (16,3,256,256)
  size_t f_spm  = alloc(1048576);
  size_t f_spx  = alloc(1048576);
  size_t f_sam  = alloc(1048576);
  size_t f_gpart= alloc(5120);
  size_t f_chw  = alloc(80);
  size_t f_bnsb = alloc(8);
  size_t f_mnmx = alloc(96);
  size_t f_counts=alloc(512);
  size_t f_lossp= alloc(256);
  size_t f_cb2  = alloc(512);
  size_t f_idx  = alloc(65536);
  size_t f_vqkey= alloc(131072);    // 65536 x u64 keys
  size_t f_wt_e1= alloc(3072);
  size_t f_wt_e2= alloc(131072);
  size_t f_wt_e3= alloc(147456);
  size_t f_wt_ra1=alloc(36864);
  size_t f_wt_rb1=alloc(4096);
  size_t f_wt_ra2=alloc(36864);
  size_t f_wt_rb2=alloc(4096);
  size_t f_wt_ep= alloc(8192);
  size_t f_wt_d1= alloc(73728);
  size_t f_wt_da1=alloc(36864);
  size_t f_wt_db1=alloc(4096);
  size_t f_wt_da2=alloc(36864);
  size_t f_wt_db2=alloc(4096);
  size_t f_wt_d2= alloc(131072);
  size_t f_wt_d3= alloc(5120);
  if (ws_size < o*sizeof(float)) return;

  float* t    = ws + f_buf3;
  float* zenc = ws + f_buf3;
  float* h1   = ws + f_buf0;
  float* zq   = ws + f_buf0;
  float* dh2  = ws + f_buf0;
  float* h2   = ws + f_buf1;
  float* dh1  = ws + f_buf1;
  float* h3   = ws + f_buf2;
  float* t3   = ws + f_buf4;
  float* spm  = ws + f_spm;
  float* spx  = ws + f_spx;
  float* rtmp = ws + f_spm;
  float* samap= ws + f_sam;
  unsigned* mnmx = (unsigned*)(ws + f_mnmx);
  int* idx = (int*)(ws + f_idx);
  unsigned long long* vqkeys = (unsigned long long*)(ws + f_vqkey);

  dim3 T(256);

  k_init<<<1, 512, 0, stream>>>(ws + f_counts, mnmx);
  k_initvq<<<256, T, 0, stream>>>(vqkeys);

  // weight packs
  k_pack<<<(3072+255)/256, T, 0, stream>>>(e1_w, ws+f_wt_e1, 3, 64, 16);
  k_pack<<<(131072+255)/256, T, 0, stream>>>(e2_w, ws+f_wt_e2, 64, 128, 16);
  k_pack<<<(147456+255)/256, T, 0, stream>>>(e3_w, ws+f_wt_e3, 128, 128, 9);
  k_pack<<<(36864+255)/256, T, 0, stream>>>(er1a_w, ws+f_wt_ra1, 128, 32, 9);
  k_pack<<<(4096+255)/256, T, 0, stream>>>(er1b_w, ws+f_wt_rb1, 32, 128, 1);
  k_pack<<<(36864+255)/256, T, 0, stream>>>(er2a_w, ws+f_wt_ra2, 128, 32, 9);
  k_pack<<<(4096+255)/256, T, 0, stream>>>(er2b_w, ws+f_wt_rb2, 32, 128, 1);
  k_pack<<<(8192+255)/256, T, 0, stream>>>(ep_w, ws+f_wt_ep, 128, 64, 1);
  k_pack_d1<<<(73728+255)/256, T, 0, stream>>>(d1_w, ws+f_wt_d1);
  k_pack<<<(36864+255)/256, T, 0, stream>>>(dr1a_w, ws+f_wt_da1, 128, 32, 9);
  k_pack<<<(4096+255)/256, T, 0, stream>>>(dr1b_w, ws+f_wt_db1, 32, 128, 1);
  k_pack<<<(36864+255)/256, T, 0, stream>>>(dr2a_w, ws+f_wt_da2, 128, 32, 9);
  k_pack<<<(4096+255)/256, T, 0, stream>>>(dr2b_w, ws+f_wt_db2, 32, 128, 1);
  k_pack_d2p<<<512, T, 0, stream>>>(d2_w, ws+f_wt_d2);
  k_pack_d3p<<<20, T, 0, stream>>>(d3_w, ws+f_wt_d3);
  k_cb2<<<8, 64, 0, stream>>>(cb, ws+f_cb2);

  // front
  k_taylor<<<5120, T, 0, stream>>>(x, tc, t, ws+f_gpart);
  k_chw<<<1, 128, 0, stream>>>(ws+f_gpart, ca_w1, ca_b1, ca_w2, ca_b2, bn_g, bn_b, bn_m, bn_v,
                               ws+f_chw, ws+f_bnsb);
  k_spin<<<dim3(256,16), T, 0, stream>>>(t, ws+f_chw, spm, spx);
  k_sa<<<dim3(256,16), T, 0, stream>>>(spm, spx, sa_w, sa_b, samap);
  k_mix<<<dim3(256,16), T, 0, stream>>>(t, samap, mix_w, mix_b, ws+f_bnsb, t3, mnmx);
  k_norm<<<12288, T, 0, stream>>>(t3, mnmx);

  // encoder
  convk16<<<dim3(64,4,16), T, 0, stream>>>(t3, ws+f_wt_e1, e1_b, h1);
  // e2: ROWS=4 (best config; CO=16 and U=4 variants both regressed)
  conv8s2<64,128,4,false,true><<<dim3(4,16,16), T, 0, stream>>>(h1, ws+f_wt_e2, e2_b, h2);
  // e3: ROWS=4, U=2
  conv8<128,128,3,3,1,1,4,2,false,false,false><<<dim3(4,16,16), T, 0, stream>>>(h2, ws+f_wt_e3, e3_b, nullptr, h3, 4096,64,1,0);
  // res 3x3 128->32: ROWS=1 -> 1024 blocks = 4/CU
  conv8<128,32,3,3,1,1,1,2,true,true,false><<<dim3(16,4,16), T, 0, stream>>>(h3, ws+f_wt_ra1, er1a_b, nullptr, rtmp, 4096,64,1,0);
  conv8<32,128,1,1,0,0,2,4,false,false,true><<<dim3(8,16,16), T, 0, stream>>>(rtmp, ws+f_wt_rb1, er1b_b, h3, h3, 4096,64,1,0);
  conv8<128,32,3,3,1,1,1,2,true,true,false><<<dim3(16,4,16), T, 0, stream>>>(h3, ws+f_wt_ra2, er2a_b, nullptr, rtmp, 4096,64,1,0);
  conv8<32,128,1,1,0,0,2,4,false,false,true><<<dim3(8,16,16), T, 0, stream>>>(rtmp, ws+f_wt_rb2, er2b_b, h3, h3, 4096,64,1,0);
  conv8<128,64,1,1,0,0,2,4,true,false,false><<<dim3(8,8,16), T, 0, stream>>>(h3, ws+f_wt_ep, ep_b, nullptr, zenc, 4096,64,1,0);

  // VQ: codebook split across 4 block-columns (coalescing preserved), then finalize pass
  k_vqscan<<<dim3(256,4), T, 0, stream>>>(zenc, cb, ws+f_cb2, vqkeys);
  k_vqfin<<<256, T, 0, stream>>>(zenc, cb, vqkeys, idx, ws+f_lossp, ws+f_counts);
  k_finalize<<<1, 512, 0, stream>>>(ws+f_counts, ws+f_lossp, out);
  k_gather<<<16384, T, 0, stream>>>(cb, idx, zq);

  // decoder
  // d1: ROWS=4, U=2
  conv8<64,128,3,3,1,1,4,2,false,false,false><<<dim3(4,16,16), T, 0, stream>>>(zq, ws+f_wt_d1, d1_b, nullptr, dh1, 4096,64,1,0);
  conv8<128,32,3,3,1,1,1,2,true,true,false><<<dim3(16,4,16), T, 0, stream>>>(dh1, ws+f_wt_da1, dr1a_b, nullptr, rtmp, 4096,64,1,0);
  conv8<32,128,1,1,0,0,2,4,false,false,true><<<dim3(8,16,16), T, 0, stream>>>(rtmp, ws+f_wt_db1, dr1b_b, dh1, dh1, 4096,64,1,0);
  conv8<128,32,3,3,1,1,1,2,true,true,false><<<dim3(16,4,16), T, 0, stream>>>(dh1, ws+f_wt_da2, dr2a_b, nullptr, rtmp, 4096,64,1,0);
  conv8<32,128,1,1,0,0,2,4,false,false,true><<<dim3(8,16,16), T, 0, stream>>>(rtmp, ws+f_wt_db2, dr2b_b, dh1, dh1, 4096,64,1,0);
  // d2: both px parities per block, ROWS=4; grid 1024 = 4/CU
  convd2p<<<dim3(4,16,16), T, 0, stream>>>(dh1, ws+f_wt_d2, d2_b, dh2);
  // d3: all 4 parities fused in one 1024-block launch (parity = blockIdx.y)
  convd3<<<dim3(16,4,16), T, 0, stream>>>(dh2, ws+f_wt_d3, d3_b, out);
}